// Round 6
// baseline (400.522 us; speedup 1.0000x reference)
//
#include <hip/hip_runtime.h>
#include <hip/hip_bf16.h>
#include <math.h>

#define B_SZ 2
#define SEQLEN 2048
#define D_MODEL 1024
#define D_INNER 2048
#define D_STATE 16
#define D_CONV 4
#define DT_RANK 64
#define NTOK (B_SZ * SEQLEN)      /* 4096 */
#define XDBL 96                   /* DT_RANK + 2*D_STATE */
#define NC 32                     /* scan chunks */
#define LC 64                     /* chunk length */
#define PADTOT (17 * 256)         /* padded perm length (256-aligned experts) */

typedef float f32x4 __attribute__((ext_vector_type(4)));
typedef unsigned int u32x4 __attribute__((ext_vector_type(4)));
typedef __hip_bfloat16 bf16;

__device__ __forceinline__ float siluf(float v) { return v / (1.f + __expf(-v)); }
__device__ __forceinline__ float softplusf(float v) { return (v > 20.f) ? v : log1pf(__expf(v)); }

__device__ __forceinline__ void mfma_bf16(f32x4& acc, u32x4 a, u32x4 b) {
  asm("v_mfma_f32_16x16x32_bf16 %0, %1, %2, %0" : "+v"(acc) : "v"(a), "v"(b));
}

// async global->LDS, 16B per lane; LDS dest is wave-uniform base + lane*16
__device__ __forceinline__ void gload16(const bf16* g, bf16* l) {
  __builtin_amdgcn_global_load_lds(
      (const __attribute__((address_space(1))) unsigned int*)g,
      (__attribute__((address_space(3))) unsigned int*)l, 16, 0, 0);
}

// ---- token partition by expert, padded so every 256-row panel is pure-expert.
__global__ __launch_bounds__(1024) void k_perm(const int* __restrict__ ids, int* __restrict__ perm) {
  __shared__ int sc[1024];
  const int tid = threadIdx.x;
  int loc[4];
  int cnt = 0;
#pragma unroll
  for (int q = 0; q < 4; q++) {
    loc[q] = ids[tid * 4 + q];
    cnt += (loc[q] == 0);
  }
  sc[tid] = cnt;
  __syncthreads();
  for (int off = 1; off < 1024; off <<= 1) {
    int v = sc[tid];
    int u = (tid >= off) ? sc[tid - off] : 0;
    __syncthreads();
    sc[tid] = v + u;
    __syncthreads();
  }
  const int N0 = sc[1023];
  const int m0 = (N0 + 255) & ~255;
  const int N1 = NTOK - N0;
  for (int idx = tid; idx < PADTOT; idx += 1024)
    if ((idx >= N0 && idx < m0) || idx >= m0 + N1) perm[idx] = -1;
  int zb = sc[tid] - cnt;
#pragma unroll
  for (int q = 0; q < 4; q++) {
    int t = tid * 4 + q;
    if (loc[q] == 0) { perm[zb] = t; zb++; }
    else             { perm[m0 + (t - zb)] = t; }
  }
}

// ---- fused fp32 -> bf16 conversion of h and all GEMM weights
#define CVT_H   (NTOK * D_MODEL)
#define CVT_WIN (2 * 2 * D_INNER * D_MODEL)
#define CVT_WX  (2 * XDBL * D_INNER)
#define CVT_WDT (2 * D_INNER * DT_RANK)
#define CVT_WO  (2 * D_MODEL * D_INNER)
#define CVT_TOT (CVT_H + CVT_WIN + CVT_WX + CVT_WDT + CVT_WO)
__global__ __launch_bounds__(256) void k_cvtall(const float* __restrict__ h,
                                                const float* __restrict__ Win,
                                                const float* __restrict__ Wx,
                                                const float* __restrict__ Wdt,
                                                const float* __restrict__ Wout,
                                                bf16* __restrict__ hB, bf16* __restrict__ WinB,
                                                bf16* __restrict__ WxB, bf16* __restrict__ WdtB,
                                                bf16* __restrict__ WoB) {
  size_t i = ((size_t)blockIdx.x * 256 + threadIdx.x) * 8;
  const float* src; bf16* dst; size_t off;
  if (i < CVT_H)                          { src = h;    dst = hB;   off = i; }
  else if (i < CVT_H + CVT_WIN)           { src = Win;  dst = WinB; off = i - CVT_H; }
  else if (i < CVT_H + CVT_WIN + CVT_WX)  { src = Wx;   dst = WxB;  off = i - CVT_H - CVT_WIN; }
  else if (i < CVT_TOT - CVT_WO)          { src = Wdt;  dst = WdtB; off = i - CVT_H - CVT_WIN - CVT_WX; }
  else                                    { src = Wout; dst = WoB;  off = i - (CVT_TOT - CVT_WO); }
  float4 f0 = *(const float4*)&src[off];
  float4 f1 = *(const float4*)&src[off + 4];
  __align__(16) bf16 tmp[8];
  tmp[0] = __float2bfloat16(f0.x); tmp[1] = __float2bfloat16(f0.y);
  tmp[2] = __float2bfloat16(f0.z); tmp[3] = __float2bfloat16(f0.w);
  tmp[4] = __float2bfloat16(f1.x); tmp[5] = __float2bfloat16(f1.y);
  tmp[6] = __float2bfloat16(f1.z); tmp[7] = __float2bfloat16(f1.w);
  *(u32x4*)&dst[off] = *(const u32x4*)tmp;
}

// ---- 256x256-tile bf16 MFMA expert GEMM for the in-projection (N=4096, K=1024).
// 8 waves (2M x 4N), BK=64, 2-barrier m97 loop, global_load_lds w=16, linear LDS.
// Column-major block chunking: each XCD chunk = few W-column panels x many rows,
// so the 1MB W slice stays L2-resident and is reused by all row panels.
// EPI: split col<2048 -> out0 (x_raw), else out1 (z).
__global__ __launch_bounds__(512) void k_gemmBig(const bf16* __restrict__ actB,
                                                 const int* __restrict__ perm,
                                                 const int* __restrict__ ids,
                                                 const bf16* __restrict__ WB,
                                                 float* __restrict__ out0,
                                                 float* __restrict__ out1) {
  constexpr int KDIM = D_MODEL;
  constexpr int NW = 2 * D_INNER;
  __shared__ bf16 As[256 * 64];
  __shared__ bf16 Ws[256 * 64];
  __shared__ int permL[256];
  const int tid = threadIdx.x;

  // bijective XCD swizzle + column-major unpack (consecutive swz = same column)
  const int gy = gridDim.y;                 // 17 row panels
  const int nwg = gridDim.x * gy;           // 272, %8==0
  const int fid = blockIdx.y * gridDim.x + blockIdx.x;
  const int q8 = nwg >> 3;
  const int swz = (fid & 7) * q8 + (fid >> 3);
  const int bx = swz / gy, by = swz % gy;

  const int ot = bx * 256;
  const int tt = by * 256;
  if (tid < 256) permL[tid] = perm[tt + tid];

  const int lane = tid & 63, w = tid >> 6;   // 8 waves
  const int wr = w >> 2, wc = w & 3;         // 2M x 4N
  const int lr = lane & 15, lg = lane >> 4;

  const int t00 = perm[tt];
  const int eu = (t00 >= 0) ? ids[t00] : 0;
  const size_t wexp = (size_t)eu * NW * KDIM;

  // staging: wave w covers rows [w*32, w*32+32); instr v covers 8 rows
  const int srow = w * 32 + (lane >> 3);
  const int scol = (lane & 7) * 8;
  size_t abase[4], bbase[4];
  int ldsoff[4];
#pragma unroll
  for (int v = 0; v < 4; v++) {
    const int row = srow + v * 8;
    int ta = perm[tt + row];
    if (ta < 0) ta = 0;
    abase[v] = (size_t)ta * KDIM + scol;
    bbase[v] = wexp + (size_t)(ot + row) * KDIM + scol;
    ldsoff[v] = (w * 32 + v * 8) * 64;
  }

  f32x4 acc[8][4];
#pragma unroll
  for (int i = 0; i < 8; i++)
#pragma unroll
    for (int j = 0; j < 4; j++) acc[i][j] = (f32x4){0.f, 0.f, 0.f, 0.f};

  for (int k0 = 0; k0 < KDIM; k0 += 64) {
#pragma unroll
    for (int v = 0; v < 4; v++) {
      gload16(&actB[abase[v] + k0], &As[ldsoff[v]]);
      gload16(&WB[bbase[v] + k0], &Ws[ldsoff[v]]);
    }
    __syncthreads();
#pragma unroll
    for (int ks = 0; ks < 64; ks += 32) {
      u32x4 a[8], b[4];
#pragma unroll
      for (int f = 0; f < 8; f++)
        a[f] = *(const u32x4*)&As[(wr * 128 + f * 16 + lr) * 64 + ks + lg * 8];
#pragma unroll
      for (int j = 0; j < 4; j++)
        b[j] = *(const u32x4*)&Ws[(wc * 64 + j * 16 + lr) * 64 + ks + lg * 8];
#pragma unroll
      for (int i = 0; i < 8; i++)
#pragma unroll
        for (int j = 0; j < 4; j++) mfma_bf16(acc[i][j], a[i], b[j]);
    }
    __syncthreads();
  }

#pragma unroll
  for (int i = 0; i < 8; i++) {
#pragma unroll
    for (int r = 0; r < 4; r++) {
      const int m = wr * 128 + i * 16 + lg * 4 + r;
      const int t = permL[m];
      if (t < 0) continue;
#pragma unroll
      for (int j = 0; j < 4; j++) {
        const int col = ot + wc * 64 + j * 16 + lr;
        const float v = acc[i][j][r];
        if (col < D_INNER) out0[(size_t)t * D_INNER + col] = v;
        else out1[(size_t)t * D_INNER + (col - D_INNER)] = v;
      }
    }
  }
}

// ---- 128x128-tile bf16 MFMA expert GEMM (R3-proven 2-barrier body) + XCD swizzle.
// Row-major chunking (consecutive swz = same row panel -> A-reuse in L2).
// EPI 0: out0[t*LDO+col] fp32
// EPI 2: out0 = softplus(acc + bias[e*NW+col])
// EPI 3: split-K partial: out0[(kz*NTOK+t)*XDBL+col], col<XDBL
template <int KDIM, int NW, int LDO, int EPI, int KSPLIT>
__global__ __launch_bounds__(256) void k_gemmG(const bf16* __restrict__ actB,
                                               const int* __restrict__ perm,
                                               const int* __restrict__ ids,
                                               const bf16* __restrict__ WB,
                                               const float* __restrict__ bias,
                                               float* __restrict__ out0) {
  static_assert(KDIM % (64 * KSPLIT) == 0, "K split");
  constexpr int KLEN = KDIM / KSPLIT;
  __shared__ bf16 As[128 * 64];
  __shared__ bf16 Ws[128 * 64];
  __shared__ int permL[128];
  const int tid = threadIdx.x;

  const int gx = gridDim.x;
  const int nwg = gx * gridDim.y;
  const int fid = blockIdx.y * gx + blockIdx.x;
  const int q8 = nwg >> 3;
  const int swz = (fid & 7) * q8 + (fid >> 3);
  const int bx = swz % gx, by = swz / gx;

  const int ot = (KSPLIT > 1) ? 0 : bx * 128;
  const int kz = (KSPLIT > 1) ? bx : 0;
  const int kbase = kz * KLEN;
  const int tt = by * 128;

  if (tid < 128) permL[tid] = perm[tt + tid];

  const int lane = tid & 63, w = tid >> 6;
  const int wr = w >> 1, wc = w & 1;
  const int lr = lane & 15, lg = lane >> 4;

  const int t00 = perm[tt];
  const int eu = (t00 >= 0) ? ids[t00] : 0;
  const size_t wexp = (size_t)eu * NW * KDIM;

  const int srow = w * 32 + (lane >> 3);
  const int scol = (lane & 7) * 8;
  size_t abase[4], bbase[4];
  int ldsoff[4];
#pragma unroll
  for (int v = 0; v < 4; v++) {
    const int row = srow + v * 8;
    int ta = perm[tt + row];
    if (ta < 0) ta = 0;
    abase[v] = (size_t)ta * KDIM + scol;
    int orow = ot + row;
    if (NW % 128 != 0) orow = (orow < NW) ? orow : (NW - 1);
    bbase[v] = wexp + (size_t)orow * KDIM + scol;
    ldsoff[v] = (w * 32 + v * 8) * 64;
  }

  f32x4 acc[4][4];
#pragma unroll
  for (int i = 0; i < 4; i++)
#pragma unroll
    for (int j = 0; j < 4; j++) acc[i][j] = (f32x4){0.f, 0.f, 0.f, 0.f};

  for (int k0 = kbase; k0 < kbase + KLEN; k0 += 64) {
#pragma unroll
    for (int v = 0; v < 4; v++) {
      gload16(&actB[abase[v] + k0], &As[ldsoff[v]]);
      gload16(&WB[bbase[v] + k0], &Ws[ldsoff[v]]);
    }
    __syncthreads();
#pragma unroll
    for (int ks = 0; ks < 64; ks += 32) {
      u32x4 a[4], b[4];
#pragma unroll
      for (int f = 0; f < 4; f++)
        a[f] = *(const u32x4*)&As[(wr * 64 + f * 16 + lr) * 64 + ks + lg * 8];
#pragma unroll
      for (int f = 0; f < 4; f++)
        b[f] = *(const u32x4*)&Ws[(wc * 64 + f * 16 + lr) * 64 + ks + lg * 8];
#pragma unroll
      for (int i = 0; i < 4; i++)
#pragma unroll
        for (int j = 0; j < 4; j++) mfma_bf16(acc[i][j], a[i], b[j]);
    }
    __syncthreads();
  }

#pragma unroll
  for (int i = 0; i < 4; i++) {
#pragma unroll
    for (int r = 0; r < 4; r++) {
      const int m = wr * 64 + i * 16 + lg * 4 + r;
      const int t = permL[m];
      if (t < 0) continue;
#pragma unroll
      for (int j = 0; j < 4; j++) {
        const int col = ot + wc * 64 + j * 16 + lr;
        float v = acc[i][j][r];
        if (EPI == 0) {
          out0[(size_t)t * LDO + col] = v;
        } else if (EPI == 2) {
          v = softplusf(v + bias[eu * NW + col]);
          out0[(size_t)t * LDO + col] = v;
        } else if (EPI == 3) {
          if (col < XDBL) out0[((size_t)kz * NTOK + t) * XDBL + col] = v;
        }
      }
    }
  }
}

// ---- reduce split-K partials -> xdbl fp32 + bf16 dt-input (cols 0..63)
__global__ __launch_bounds__(256) void k_xred(const float* __restrict__ part,
                                              float* __restrict__ xdbl,
                                              bf16* __restrict__ x64B) {
  const int i = blockIdx.x * 256 + threadIdx.x;  // over NTOK*XDBL
  float s = 0.f;
#pragma unroll
  for (int k = 0; k < 8; k++) s += part[(size_t)k * NTOK * XDBL + i];
  xdbl[i] = s;
  const int t = i / XDBL, col = i - t * XDBL;
  if (col < DT_RANK) x64B[(size_t)t * DT_RANK + col] = __float2bfloat16(s);
}

// ---- depthwise causal conv + SiLU; emits fp32 x_act and bf16 xB
__global__ __launch_bounds__(256) void k_conv(const float* __restrict__ x_raw,
                                              const float* __restrict__ cw,
                                              const float* __restrict__ cb,
                                              float* __restrict__ x_act,
                                              bf16* __restrict__ xB) {
  int idx = blockIdx.x * 256 + threadIdx.x;
  int c = idx & (D_INNER - 1);
  int t = idx >> 11;
  int l = t & (SEQLEN - 1);
  int b = t >> 11;
  float acc = cb[c];
#pragma unroll
  for (int k = 0; k < D_CONV; k++) {
    int ll = l + k - (D_CONV - 1);
    if (ll >= 0)
      acc = fmaf(cw[c * D_CONV + k], x_raw[((size_t)(b * SEQLEN + ll)) * D_INNER + c], acc);
  }
  float s = siluf(acc);
  x_act[(size_t)idx] = s;
  xB[(size_t)idx] = __float2bfloat16(s);
}

// ---- scan pass A: per-chunk local scan -> F, Sdt
__global__ __launch_bounds__(256) void k_scan_part(const float* __restrict__ x_act,
                                                   const float* __restrict__ dtb,
                                                   const float* __restrict__ xdbl,
                                                   const float* __restrict__ A_log,
                                                   float* __restrict__ F,
                                                   float* __restrict__ Sdt) {
  __shared__ float Bs[LC][D_STATE];
  const int tid = threadIdx.x;
  const int j = blockIdx.y;
  const int ch = blockIdx.x * 256 + tid;
  const int b = ch >> 11, c = ch & (D_INNER - 1);
  const int t0 = (b << 11) + j * LC;
  {
    int l = tid >> 2, q = (tid & 3) * 4;
    *(float4*)&Bs[l][q] = *(const float4*)&xdbl[(size_t)(t0 + l) * XDBL + DT_RANK + q];
  }
  float Ar[D_STATE];
#pragma unroll
  for (int n4 = 0; n4 < 4; n4++) {
    float4 a = *(const float4*)&A_log[(size_t)c * D_STATE + n4 * 4];
    Ar[n4 * 4 + 0] = -__expf(a.x); Ar[n4 * 4 + 1] = -__expf(a.y);
    Ar[n4 * 4 + 2] = -__expf(a.z); Ar[n4 * 4 + 3] = -__expf(a.w);
  }
  __syncthreads();
  float st[D_STATE];
#pragma unroll
  for (int n = 0; n < D_STATE; n++) st[n] = 0.f;
  float sdt = 0.f;
  float dtc = dtb[(size_t)t0 * D_INNER + c];
  float xc = x_act[(size_t)t0 * D_INNER + c];
  for (int l = 0; l < LC; l++) {
    float dtn = 0.f, xn = 0.f;
    if (l < LC - 1) {
      dtn = dtb[(size_t)(t0 + l + 1) * D_INNER + c];
      xn = x_act[(size_t)(t0 + l + 1) * D_INNER + c];
    }
    const float dtx = dtc * xc;
    sdt += dtc;
#pragma unroll
    for (int n = 0; n < D_STATE; n++) {
      float dA = __expf(dtc * Ar[n]);
      st[n] = fmaf(st[n], dA, dtx * Bs[l][n]);
    }
    dtc = dtn; xc = xn;
  }
  const size_t fb = ((size_t)j * NTOK + ch) * D_STATE;
#pragma unroll
  for (int n4 = 0; n4 < 4; n4++)
    *(float4*)&F[fb + n4 * 4] = make_float4(st[n4 * 4], st[n4 * 4 + 1], st[n4 * 4 + 2], st[n4 * 4 + 3]);
  Sdt[(size_t)j * NTOK + ch] = sdt;
}

// ---- scan pass B: sequential combine across chunks -> s0 per chunk
__global__ __launch_bounds__(256) void k_combine(const float* __restrict__ F,
                                                 const float* __restrict__ Sdt,
                                                 const float* __restrict__ A_log,
                                                 float* __restrict__ s0) {
  const int gid = blockIdx.x * 256 + threadIdx.x;
  const int ch = gid >> 4, n = gid & 15, c = ch & (D_INNER - 1);
  const float Ar = -__expf(A_log[(size_t)c * D_STATE + n]);
  float s = 0.f;
  for (int j = 0; j < NC; j++) {
    s0[((size_t)j * NTOK + ch) * D_STATE + n] = s;
    s = fmaf(s, __expf(Ar * Sdt[(size_t)j * NTOK + ch]), F[((size_t)j * NTOK + ch) * D_STATE + n]);
  }
}

// ---- scan pass C: recompute with s0, emit yB = bf16((scan + x*D) * silu(z))
__global__ __launch_bounds__(256) void k_scan_fin(const float* __restrict__ x_act,
                                                  const float* __restrict__ dtb,
                                                  const float* __restrict__ xdbl,
                                                  const float* __restrict__ z_buf,
                                                  const float* __restrict__ A_log,
                                                  const float* __restrict__ Dp,
                                                  const float* __restrict__ s0,
                                                  bf16* __restrict__ ybuf) {
  __shared__ float Bs[LC][D_STATE];
  __shared__ float Cs[LC][D_STATE];
  const int tid = threadIdx.x;
  const int j = blockIdx.y;
  const int ch = blockIdx.x * 256 + tid;
  const int b = ch >> 11, c = ch & (D_INNER - 1);
  const int t0 = (b << 11) + j * LC;
  {
    int l = tid >> 2, q = (tid & 3) * 4;
    *(float4*)&Bs[l][q] = *(const float4*)&xdbl[(size_t)(t0 + l) * XDBL + DT_RANK + q];
    *(float4*)&Cs[l][q] = *(const float4*)&xdbl[(size_t)(t0 + l) * XDBL + DT_RANK + D_STATE + q];
  }
  float Ar[D_STATE];
#pragma unroll
  for (int n4 = 0; n4 < 4; n4++) {
    float4 a = *(const float4*)&A_log[(size_t)c * D_STATE + n4 * 4];
    Ar[n4 * 4 + 0] = -__expf(a.x); Ar[n4 * 4 + 1] = -__expf(a.y);
    Ar[n4 * 4 + 2] = -__expf(a.z); Ar[n4 * 4 + 3] = -__expf(a.w);
  }
  __syncthreads();
  float st[D_STATE];
  const size_t sb = ((size_t)j * NTOK + ch) * D_STATE;
#pragma unroll
  for (int n4 = 0; n4 < 4; n4++) {
    float4 s = *(const float4*)&s0[sb + n4 * 4];
    st[n4 * 4 + 0] = s.x; st[n4 * 4 + 1] = s.y; st[n4 * 4 + 2] = s.z; st[n4 * 4 + 3] = s.w;
  }
  const float Dc = Dp[c];
  float dtc = dtb[(size_t)t0 * D_INNER + c];
  float xc = x_act[(size_t)t0 * D_INNER + c];
  for (int l = 0; l < LC; l++) {
    float dtn = 0.f, xn = 0.f;
    if (l < LC - 1) {
      dtn = dtb[(size_t)(t0 + l + 1) * D_INNER + c];
      xn = x_act[(size_t)(t0 + l + 1) * D_INNER + c];
    }
    const float zv = z_buf[(size_t)(t0 + l) * D_INNER + c];
    const float dtx = dtc * xc;
    float y = 0.f;
#pragma unroll
    for (int n = 0; n < D_STATE; n++) {
      float dA = __expf(dtc * Ar[n]);
      st[n] = fmaf(st[n], dA, dtx * Bs[l][n]);
      y = fmaf(st[n], Cs[l][n], y);
    }
    float yv = fmaf(xc, Dc, y);
    ybuf[(size_t)(t0 + l) * D_INNER + c] = __float2bfloat16(yv * siluf(zv));
    dtc = dtn; xc = xn;
  }
}

extern "C" void kernel_launch(void* const* d_in, const int* in_sizes, int n_in,
                              void* d_out, int out_size, void* d_ws, size_t ws_size,
                              hipStream_t stream) {
  const float* h = (const float*)d_in[0];
  const int* ids = (const int*)d_in[1];
  const float* Win = (const float*)d_in[2];
  const float* cw = (const float*)d_in[3];
  const float* cb = (const float*)d_in[4];
  const float* Wx = (const float*)d_in[5];
  const float* Wdt = (const float*)d_in[6];
  const float* bdt = (const float*)d_in[7];
  const float* Alog = (const float*)d_in[8];
  const float* Dp = (const float*)d_in[9];
  const float* Wout = (const float*)d_in[10];
  float* out = (float*)d_out;

  const size_t NTD = (size_t)NTOK * D_INNER;  // 8,388,608
  float* ws = (float*)d_ws;
  float* x_act = ws + 0 * NTD;   // fp32 x_act; hosts hB (bf16) before conv
  float* z_buf = ws + 1 * NTD;
  float* dtb_p = ws + 2 * NTD;   // fp32 dt; hosts WinB, then xdbl split-K partials
  float* xraw_p = ws + 3 * NTD;  // fp32 pre-conv x -> F -> yB (sequentially dead aliases)
  size_t cur = 4 * NTD;
  float* xdbl_p = ws + cur; cur += (size_t)NTOK * XDBL;
  float* sdt_p = ws + cur; cur += (size_t)NC * NTOK;
  int* perm = (int*)(ws + cur); cur += PADTOT;
  bf16* xB = (bf16*)(ws + cur); cur += NTD / 2;
  bf16* WoB = (bf16*)(ws + cur); cur += CVT_WO / 2;
  bf16* WxB = (bf16*)(ws + cur); cur += CVT_WX / 2;
  bf16* WdtB = (bf16*)(ws + cur); cur += CVT_WDT / 2;
  bf16* x64B = (bf16*)(ws + cur); cur += (size_t)NTOK * DT_RANK / 2;

  bf16* hB = (bf16*)x_act;        // dead after in-proj
  bf16* WinB = (bf16*)dtb_p;      // dead after in-proj
  float* part = dtb_p;            // xdbl split-K partials (8*4096*96 f32), dead before dt GEMM
  float* F = xraw_p;              // x_raw dead after conv
  bf16* yB = (bf16*)xraw_p;       // F dead after combine
  float* s0 = (float*)d_out;      // scratch in d_out, fully overwritten by out-proj

  k_perm<<<1, 1024, 0, stream>>>(ids, perm);
  k_cvtall<<<CVT_TOT / 8 / 256, 256, 0, stream>>>(h, Win, Wx, Wdt, Wout, hB, WinB, WxB, WdtB, WoB);
  k_gemmBig<<<dim3(16, 17), 512, 0, stream>>>(hB, perm, ids, WinB, xraw_p, z_buf);
  k_conv<<<NTD / 256, 256, 0, stream>>>(xraw_p, cw, cb, x_act, xB);
  k_gemmG<D_INNER, XDBL, XDBL, 3, 8>
      <<<dim3(8, 34), 256, 0, stream>>>(xB, perm, ids, WxB, nullptr, part);
  k_xred<<<NTOK * XDBL / 256, 256, 0, stream>>>(part, xdbl_p, x64B);
  k_gemmG<DT_RANK, D_INNER, D_INNER, 2, 1>
      <<<dim3(16, 34), 256, 0, stream>>>(x64B, perm, ids, WdtB, bdt, dtb_p);
  k_scan_part<<<dim3(16, NC), 256, 0, stream>>>(x_act, dtb_p, xdbl_p, Alog, F, sdt_p);
  k_combine<<<256, 256, 0, stream>>>(F, sdt_p, Alog, s0);
  k_scan_fin<<<dim3(16, NC), 256, 0, stream>>>(x_act, dtb_p, xdbl_p, z_buf, Alog, Dp, s0, yB);
  k_gemmG<D_INNER, D_MODEL, D_MODEL, 0, 1>
      <<<dim3(8, 34), 256, 0, stream>>>(yB, perm, ids, WoB, nullptr, out);
}

// Round 7
// 342.204 us; speedup vs baseline: 1.1704x; 1.1704x over previous
//
#include <hip/hip_runtime.h>
#include <hip/hip_bf16.h>
#include <math.h>

#define B_SZ 2
#define SEQLEN 2048
#define D_MODEL 1024
#define D_INNER 2048
#define D_STATE 16
#define D_CONV 4
#define DT_RANK 64
#define NTOK (B_SZ * SEQLEN)      /* 4096 */
#define XDBL 96                   /* DT_RANK + 2*D_STATE */
#define NC 32                     /* scan chunks */
#define LC 64                     /* chunk length */
#define PADTOT (34 * 128)         /* padded perm length (128-aligned experts) */

typedef float f32x4 __attribute__((ext_vector_type(4)));
typedef unsigned int u32x4 __attribute__((ext_vector_type(4)));
typedef __hip_bfloat16 bf16;

__device__ __forceinline__ float siluf(float v) { return v / (1.f + __expf(-v)); }
__device__ __forceinline__ float softplusf(float v) { return (v > 20.f) ? v : log1pf(__expf(v)); }

__device__ __forceinline__ void mfma_bf16(f32x4& acc, u32x4 a, u32x4 b) {
  asm("v_mfma_f32_16x16x32_bf16 %0, %1, %2, %0" : "+v"(acc) : "v"(a), "v"(b));
}

// async global->LDS, 16B per lane; LDS dest is wave-uniform base + lane*16
__device__ __forceinline__ void gload16(const bf16* g, bf16* l) {
  __builtin_amdgcn_global_load_lds(
      (const __attribute__((address_space(1))) unsigned int*)g,
      (__attribute__((address_space(3))) unsigned int*)l, 16, 0, 0);
}

// ---- token partition by expert, padded so every 128-row panel is pure-expert.
__global__ __launch_bounds__(1024) void k_perm(const int* __restrict__ ids, int* __restrict__ perm) {
  __shared__ int sc[1024];
  const int tid = threadIdx.x;
  int loc[4];
  int cnt = 0;
#pragma unroll
  for (int q = 0; q < 4; q++) {
    loc[q] = ids[tid * 4 + q];
    cnt += (loc[q] == 0);
  }
  sc[tid] = cnt;
  __syncthreads();
  for (int off = 1; off < 1024; off <<= 1) {
    int v = sc[tid];
    int u = (tid >= off) ? sc[tid - off] : 0;
    __syncthreads();
    sc[tid] = v + u;
    __syncthreads();
  }
  const int N0 = sc[1023];
  const int m0 = (N0 + 127) & ~127;
  const int N1 = NTOK - N0;
  for (int idx = tid; idx < PADTOT; idx += 1024)
    if ((idx >= N0 && idx < m0) || idx >= m0 + N1) perm[idx] = -1;
  int zb = sc[tid] - cnt;
#pragma unroll
  for (int q = 0; q < 4; q++) {
    int t = tid * 4 + q;
    if (loc[q] == 0) { perm[zb] = t; zb++; }
    else             { perm[m0 + (t - zb)] = t; }
  }
}

// ---- fused fp32 -> bf16 conversion of h and all GEMM weights
#define CVT_H   (NTOK * D_MODEL)
#define CVT_WIN (2 * 2 * D_INNER * D_MODEL)
#define CVT_WX  (2 * XDBL * D_INNER)
#define CVT_WDT (2 * D_INNER * DT_RANK)
#define CVT_WO  (2 * D_MODEL * D_INNER)
#define CVT_TOT (CVT_H + CVT_WIN + CVT_WX + CVT_WDT + CVT_WO)
__global__ __launch_bounds__(256) void k_cvtall(const float* __restrict__ h,
                                                const float* __restrict__ Win,
                                                const float* __restrict__ Wx,
                                                const float* __restrict__ Wdt,
                                                const float* __restrict__ Wout,
                                                bf16* __restrict__ hB, bf16* __restrict__ WinB,
                                                bf16* __restrict__ WxB, bf16* __restrict__ WdtB,
                                                bf16* __restrict__ WoB) {
  size_t i = ((size_t)blockIdx.x * 256 + threadIdx.x) * 8;
  const float* src; bf16* dst; size_t off;
  if (i < CVT_H)                          { src = h;    dst = hB;   off = i; }
  else if (i < CVT_H + CVT_WIN)           { src = Win;  dst = WinB; off = i - CVT_H; }
  else if (i < CVT_H + CVT_WIN + CVT_WX)  { src = Wx;   dst = WxB;  off = i - CVT_H - CVT_WIN; }
  else if (i < CVT_TOT - CVT_WO)          { src = Wdt;  dst = WdtB; off = i - CVT_H - CVT_WIN - CVT_WX; }
  else                                    { src = Wout; dst = WoB;  off = i - (CVT_TOT - CVT_WO); }
  float4 f0 = *(const float4*)&src[off];
  float4 f1 = *(const float4*)&src[off + 4];
  __align__(16) bf16 tmp[8];
  tmp[0] = __float2bfloat16(f0.x); tmp[1] = __float2bfloat16(f0.y);
  tmp[2] = __float2bfloat16(f0.z); tmp[3] = __float2bfloat16(f0.w);
  tmp[4] = __float2bfloat16(f1.x); tmp[5] = __float2bfloat16(f1.y);
  tmp[6] = __float2bfloat16(f1.z); tmp[7] = __float2bfloat16(f1.w);
  *(u32x4*)&dst[off] = *(const u32x4*)tmp;
}

// ---- 128x128-tile bf16 MFMA expert GEMM (R3 single-buffer 2-barrier body).
// SWZ=1: XCD row-chunk swizzle -- each XCD owns ~nwg/8 consecutive blocks =
// few row panels x all columns (A slice L2-resident, W read once per XCD).
// EPI 0: out0[t*LDO+col] fp32
// EPI 1: col<2048 -> out0 fp32 (x_raw); else -> outb bf16 (z)
// EPI 2: out0 = softplus(acc + bias[e*NW+col]) fp32
// EPI 3: split-K partial: out0[(kz*NTOK+t)*XDBL+col], col<XDBL
template <int KDIM, int NW, int LDO, int EPI, int KSPLIT, int SWZ>
__global__ __launch_bounds__(256) void k_gemmG(const bf16* __restrict__ actB,
                                               const int* __restrict__ perm,
                                               const int* __restrict__ ids,
                                               const bf16* __restrict__ WB,
                                               const float* __restrict__ bias,
                                               float* __restrict__ out0,
                                               bf16* __restrict__ outb) {
  static_assert(KDIM % (64 * KSPLIT) == 0, "K split");
  constexpr int KLEN = KDIM / KSPLIT;
  __shared__ bf16 As[128 * 64];
  __shared__ bf16 Ws[128 * 64];
  __shared__ int permL[128];
  const int tid = threadIdx.x;

  int bx, by;
  if (SWZ) {
    const int gx = gridDim.x;
    const int nwg = gx * gridDim.y;       // divisible by 8 at all launch configs
    const int fid = blockIdx.y * gx + blockIdx.x;
    const int q8 = nwg >> 3;
    const int swz = (fid & 7) * q8 + (fid >> 3);
    bx = swz % gx;
    by = swz / gx;
  } else {
    bx = blockIdx.x;
    by = blockIdx.y;
  }

  const int ot = (KSPLIT > 1) ? 0 : bx * 128;
  const int kz = (KSPLIT > 1) ? bx : 0;
  const int kbase = kz * KLEN;
  const int tt = by * 128;

  if (tid < 128) permL[tid] = perm[tt + tid];

  const int lane = tid & 63, w = tid >> 6;
  const int wr = w >> 1, wc = w & 1;
  const int lr = lane & 15, lg = lane >> 4;

  const int t00 = perm[tt];
  const int eu = (t00 >= 0) ? ids[t00] : 0;
  const size_t wexp = (size_t)eu * NW * KDIM;

  // staging geometry: wave w covers rows [w*32, w*32+32); instr v covers 8 rows
  const int srow = w * 32 + (lane >> 3);
  const int scol = (lane & 7) * 8;
  size_t abase[4], bbase[4];
  int ldsoff[4];
#pragma unroll
  for (int v = 0; v < 4; v++) {
    const int row = srow + v * 8;
    int ta = perm[tt + row];
    if (ta < 0) ta = 0;
    abase[v] = (size_t)ta * KDIM + scol;
    int orow = ot + row;
    if (NW % 128 != 0) orow = (orow < NW) ? orow : (NW - 1);
    bbase[v] = wexp + (size_t)orow * KDIM + scol;
    ldsoff[v] = (w * 32 + v * 8) * 64;    // wave-uniform LDS base
  }

  f32x4 acc[4][4];
#pragma unroll
  for (int i = 0; i < 4; i++)
#pragma unroll
    for (int j = 0; j < 4; j++) acc[i][j] = (f32x4){0.f, 0.f, 0.f, 0.f};

  for (int k0 = kbase; k0 < kbase + KLEN; k0 += 64) {
#pragma unroll
    for (int v = 0; v < 4; v++) {
      gload16(&actB[abase[v] + k0], &As[ldsoff[v]]);
      gload16(&WB[bbase[v] + k0], &Ws[ldsoff[v]]);
    }
    __syncthreads();
#pragma unroll
    for (int ks = 0; ks < 64; ks += 32) {
      u32x4 a[4], b[4];
#pragma unroll
      for (int f = 0; f < 4; f++)
        a[f] = *(const u32x4*)&As[(wr * 64 + f * 16 + lr) * 64 + ks + lg * 8];
#pragma unroll
      for (int f = 0; f < 4; f++)
        b[f] = *(const u32x4*)&Ws[(wc * 64 + f * 16 + lr) * 64 + ks + lg * 8];
#pragma unroll
      for (int i = 0; i < 4; i++)
#pragma unroll
        for (int j = 0; j < 4; j++) mfma_bf16(acc[i][j], a[i], b[j]);
    }
    __syncthreads();
  }

  // epilogue: C row = lg*4 + r (within 16), col = lr
#pragma unroll
  for (int i = 0; i < 4; i++) {
#pragma unroll
    for (int r = 0; r < 4; r++) {
      const int m = wr * 64 + i * 16 + lg * 4 + r;
      const int t = permL[m];
      if (t < 0) continue;
#pragma unroll
      for (int j = 0; j < 4; j++) {
        const int col = ot + wc * 64 + j * 16 + lr;
        float v = acc[i][j][r];
        if (EPI == 0) {
          out0[(size_t)t * LDO + col] = v;
        } else if (EPI == 1) {
          if (col < D_INNER) out0[(size_t)t * D_INNER + col] = v;
          else outb[(size_t)t * D_INNER + (col - D_INNER)] = __float2bfloat16(v);
        } else if (EPI == 2) {
          v = softplusf(v + bias[eu * NW + col]);
          out0[(size_t)t * LDO + col] = v;
        } else if (EPI == 3) {
          if (col < XDBL) out0[((size_t)kz * NTOK + t) * XDBL + col] = v;
        }
      }
    }
  }
}

// ---- reduce split-K partials -> xdbl fp32 + bf16 dt-input (cols 0..63)
__global__ __launch_bounds__(256) void k_xred(const float* __restrict__ part,
                                              float* __restrict__ xdbl,
                                              bf16* __restrict__ x64B) {
  const int i = blockIdx.x * 256 + threadIdx.x;  // over NTOK*XDBL
  float s = 0.f;
#pragma unroll
  for (int k = 0; k < 8; k++) s += part[(size_t)k * NTOK * XDBL + i];
  xdbl[i] = s;
  const int t = i / XDBL, col = i - t * XDBL;
  if (col < DT_RANK) x64B[(size_t)t * DT_RANK + col] = __float2bfloat16(s);
}

// ---- depthwise causal conv + SiLU; emits bf16 xB only
__global__ __launch_bounds__(256) void k_conv(const float* __restrict__ x_raw,
                                              const float* __restrict__ cw,
                                              const float* __restrict__ cb,
                                              bf16* __restrict__ xB) {
  int idx = blockIdx.x * 256 + threadIdx.x;
  int c = idx & (D_INNER - 1);
  int t = idx >> 11;
  int l = t & (SEQLEN - 1);
  int b = t >> 11;
  float acc = cb[c];
#pragma unroll
  for (int k = 0; k < D_CONV; k++) {
    int ll = l + k - (D_CONV - 1);
    if (ll >= 0)
      acc = fmaf(cw[c * D_CONV + k], x_raw[((size_t)(b * SEQLEN + ll)) * D_INNER + c], acc);
  }
  xB[(size_t)idx] = __float2bfloat16(siluf(acc));
}

// ---- scan pass A: per-chunk local scan -> F, Sdt (x read as bf16)
__global__ __launch_bounds__(256) void k_scan_part(const bf16* __restrict__ xB,
                                                   const float* __restrict__ dtb,
                                                   const float* __restrict__ xdbl,
                                                   const float* __restrict__ A_log,
                                                   float* __restrict__ F,
                                                   float* __restrict__ Sdt) {
  __shared__ float Bs[LC][D_STATE];
  const int tid = threadIdx.x;
  const int j = blockIdx.y;
  const int ch = blockIdx.x * 256 + tid;
  const int b = ch >> 11, c = ch & (D_INNER - 1);
  const int t0 = (b << 11) + j * LC;
  {
    int l = tid >> 2, q = (tid & 3) * 4;
    *(float4*)&Bs[l][q] = *(const float4*)&xdbl[(size_t)(t0 + l) * XDBL + DT_RANK + q];
  }
  float Ar[D_STATE];
#pragma unroll
  for (int n4 = 0; n4 < 4; n4++) {
    float4 a = *(const float4*)&A_log[(size_t)c * D_STATE + n4 * 4];
    Ar[n4 * 4 + 0] = -__expf(a.x); Ar[n4 * 4 + 1] = -__expf(a.y);
    Ar[n4 * 4 + 2] = -__expf(a.z); Ar[n4 * 4 + 3] = -__expf(a.w);
  }
  __syncthreads();
  float st[D_STATE];
#pragma unroll
  for (int n = 0; n < D_STATE; n++) st[n] = 0.f;
  float sdt = 0.f;
  float dtc = dtb[(size_t)t0 * D_INNER + c];
  float xc = __bfloat162float(xB[(size_t)t0 * D_INNER + c]);
  for (int l = 0; l < LC; l++) {
    float dtn = 0.f, xn = 0.f;
    if (l < LC - 1) {
      dtn = dtb[(size_t)(t0 + l + 1) * D_INNER + c];
      xn = __bfloat162float(xB[(size_t)(t0 + l + 1) * D_INNER + c]);
    }
    const float dtx = dtc * xc;
    sdt += dtc;
#pragma unroll
    for (int n = 0; n < D_STATE; n++) {
      float dA = __expf(dtc * Ar[n]);
      st[n] = fmaf(st[n], dA, dtx * Bs[l][n]);
    }
    dtc = dtn; xc = xn;
  }
  const size_t fb = ((size_t)j * NTOK + ch) * D_STATE;
#pragma unroll
  for (int n4 = 0; n4 < 4; n4++)
    *(float4*)&F[fb + n4 * 4] = make_float4(st[n4 * 4], st[n4 * 4 + 1], st[n4 * 4 + 2], st[n4 * 4 + 3]);
  Sdt[(size_t)j * NTOK + ch] = sdt;
}

// ---- scan pass B: sequential combine across chunks -> s0 per chunk
__global__ __launch_bounds__(256) void k_combine(const float* __restrict__ F,
                                                 const float* __restrict__ Sdt,
                                                 const float* __restrict__ A_log,
                                                 float* __restrict__ s0) {
  const int gid = blockIdx.x * 256 + threadIdx.x;
  const int ch = gid >> 4, n = gid & 15, c = ch & (D_INNER - 1);
  const float Ar = -__expf(A_log[(size_t)c * D_STATE + n]);
  float s = 0.f;
  for (int j = 0; j < NC; j++) {
    s0[((size_t)j * NTOK + ch) * D_STATE + n] = s;
    s = fmaf(s, __expf(Ar * Sdt[(size_t)j * NTOK + ch]), F[((size_t)j * NTOK + ch) * D_STATE + n]);
  }
}

// ---- scan pass C: recompute with s0, emit yB = bf16((scan + x*D) * silu(z))
__global__ __launch_bounds__(256) void k_scan_fin(const bf16* __restrict__ xB,
                                                  const float* __restrict__ dtb,
                                                  const float* __restrict__ xdbl,
                                                  const bf16* __restrict__ zB,
                                                  const float* __restrict__ A_log,
                                                  const float* __restrict__ Dp,
                                                  const float* __restrict__ s0,
                                                  bf16* __restrict__ ybuf) {
  __shared__ float Bs[LC][D_STATE];
  __shared__ float Cs[LC][D_STATE];
  const int tid = threadIdx.x;
  const int j = blockIdx.y;
  const int ch = blockIdx.x * 256 + tid;
  const int b = ch >> 11, c = ch & (D_INNER - 1);
  const int t0 = (b << 11) + j * LC;
  {
    int l = tid >> 2, q = (tid & 3) * 4;
    *(float4*)&Bs[l][q] = *(const float4*)&xdbl[(size_t)(t0 + l) * XDBL + DT_RANK + q];
    *(float4*)&Cs[l][q] = *(const float4*)&xdbl[(size_t)(t0 + l) * XDBL + DT_RANK + D_STATE + q];
  }
  float Ar[D_STATE];
#pragma unroll
  for (int n4 = 0; n4 < 4; n4++) {
    float4 a = *(const float4*)&A_log[(size_t)c * D_STATE + n4 * 4];
    Ar[n4 * 4 + 0] = -__expf(a.x); Ar[n4 * 4 + 1] = -__expf(a.y);
    Ar[n4 * 4 + 2] = -__expf(a.z); Ar[n4 * 4 + 3] = -__expf(a.w);
  }
  __syncthreads();
  float st[D_STATE];
  const size_t sb = ((size_t)j * NTOK + ch) * D_STATE;
#pragma unroll
  for (int n4 = 0; n4 < 4; n4++) {
    float4 s = *(const float4*)&s0[sb + n4 * 4];
    st[n4 * 4 + 0] = s.x; st[n4 * 4 + 1] = s.y; st[n4 * 4 + 2] = s.z; st[n4 * 4 + 3] = s.w;
  }
  const float Dc = Dp[c];
  float dtc = dtb[(size_t)t0 * D_INNER + c];
  float xc = __bfloat162float(xB[(size_t)t0 * D_INNER + c]);
  for (int l = 0; l < LC; l++) {
    float dtn = 0.f, xn = 0.f;
    if (l < LC - 1) {
      dtn = dtb[(size_t)(t0 + l + 1) * D_INNER + c];
      xn = __bfloat162float(xB[(size_t)(t0 + l + 1) * D_INNER + c]);
    }
    const float zv = __bfloat162float(zB[(size_t)(t0 + l) * D_INNER + c]);
    const float dtx = dtc * xc;
    float y = 0.f;
#pragma unroll
    for (int n = 0; n < D_STATE; n++) {
      float dA = __expf(dtc * Ar[n]);
      st[n] = fmaf(st[n], dA, dtx * Bs[l][n]);
      y = fmaf(st[n], Cs[l][n], y);
    }
    float yv = fmaf(xc, Dc, y);
    ybuf[(size_t)(t0 + l) * D_INNER + c] = __float2bfloat16(yv * siluf(zv));
    dtc = dtn; xc = xn;
  }
}

extern "C" void kernel_launch(void* const* d_in, const int* in_sizes, int n_in,
                              void* d_out, int out_size, void* d_ws, size_t ws_size,
                              hipStream_t stream) {
  const float* h = (const float*)d_in[0];
  const int* ids = (const int*)d_in[1];
  const float* Win = (const float*)d_in[2];
  const float* cw = (const float*)d_in[3];
  const float* cb = (const float*)d_in[4];
  const float* Wx = (const float*)d_in[5];
  const float* Wdt = (const float*)d_in[6];
  const float* bdt = (const float*)d_in[7];
  const float* Alog = (const float*)d_in[8];
  const float* Dp = (const float*)d_in[9];
  const float* Wout = (const float*)d_in[10];
  float* out = (float*)d_out;

  const size_t NTD = (size_t)NTOK * D_INNER;  // 8,388,608
  float* ws = (float*)d_ws;
  float* slot0 = ws + 0 * NTD;   // hosts hB (bf16)
  float* slot1 = ws + 1 * NTD;   // hosts zB (bf16)
  float* dtb_p = ws + 2 * NTD;   // fp32 dt; hosts WinB, then xdbl split-K partials
  float* xraw_p = ws + 3 * NTD;  // fp32 pre-conv x -> F -> yB (sequentially dead aliases)
  size_t cur = 4 * NTD;
  float* xdbl_p = ws + cur; cur += (size_t)NTOK * XDBL;
  float* sdt_p = ws + cur; cur += (size_t)NC * NTOK;
  int* perm = (int*)(ws + cur); cur += PADTOT;
  bf16* xB = (bf16*)(ws + cur); cur += NTD / 2;
  bf16* WoB = (bf16*)(ws + cur); cur += CVT_WO / 2;
  bf16* WxB = (bf16*)(ws + cur); cur += CVT_WX / 2;
  bf16* WdtB = (bf16*)(ws + cur); cur += CVT_WDT / 2;
  bf16* x64B = (bf16*)(ws + cur); cur += (size_t)NTOK * DT_RANK / 2;

  bf16* hB = (bf16*)slot0;        // dead after in-proj
  bf16* zB = (bf16*)slot1;        // bf16 z, written by in-proj epilogue
  bf16* WinB = (bf16*)dtb_p;      // dead after in-proj
  float* part = dtb_p;            // xdbl split-K partials, dead before dt GEMM
  float* F = xraw_p;              // x_raw dead after conv
  bf16* yB = (bf16*)xraw_p;       // F dead after combine
  float* s0 = (float*)d_out;      // scratch in d_out, fully overwritten by out-proj

  k_perm<<<1, 1024, 0, stream>>>(ids, perm);
  k_cvtall<<<CVT_TOT / 8 / 256, 256, 0, stream>>>(h, Win, Wx, Wdt, Wout, hB, WinB, WxB, WdtB, WoB);
  k_gemmG<D_MODEL, 2 * D_INNER, 0, 1, 1, 1>
      <<<dim3(32, 34), 256, 0, stream>>>(hB, perm, ids, WinB, nullptr, xraw_p, zB);
  k_conv<<<NTD / 256, 256, 0, stream>>>(xraw_p, cw, cb, xB);
  k_gemmG<D_INNER, XDBL, XDBL, 3, 8, 0>
      <<<dim3(8, 34), 256, 0, stream>>>(xB, perm, ids, WxB, nullptr, part, nullptr);
  k_xred<<<NTOK * XDBL / 256, 256, 0, stream>>>(part, xdbl_p, x64B);
  k_gemmG<DT_RANK, D_INNER, D_INNER, 2, 1, 1>
      <<<dim3(16, 34), 256, 0, stream>>>(x64B, perm, ids, WdtB, bdt, dtb_p, nullptr);
  k_scan_part<<<dim3(16, NC), 256, 0, stream>>>(xB, dtb_p, xdbl_p, Alog, F, sdt_p);
  k_combine<<<256, 256, 0, stream>>>(F, sdt_p, Alog, s0);
  k_scan_fin<<<dim3(16, NC), 256, 0, stream>>>(xB, dtb_p, xdbl_p, zB, Alog, Dp, s0, yB);
  k_gemmG<D_INNER, D_MODEL, D_MODEL, 0, 1, 1>
      <<<dim3(8, 34), 256, 0, stream>>>(yB, perm, ids, WoB, nullptr, out, nullptr);
}